// Round 6
// baseline (893.763 us; speedup 1.0000x reference)
//
#include <hip/hip_runtime.h>
#include <math.h>

// S4 DPLR forward. B=4, L=16384, D=512, N=64. n_fft=2L=32768 via real-packed
// half-length (16384) complex FFTs, batched along contiguous d (no transposes).
//
// Round-6: stage-1 of all sweeps restructured to d-pair threads (dp=tid&15
// owns 2 consecutive d, j1=tid>>4) with float4 16-B global loads and
// ds_write_b128 LDS writes. Round-5 PMC: k_sweep1m at 3.4 TB/s, VALUBusy 48%,
// Occ 30% -> balanced VALU/mem demands, issue/latency-bound on 8-B loads.
// Stage-2 keeps (dl=tid&31, g=tid>>5) mapping (remap across barrier is free).
//
// Round-1 lesson kept: accurate sincosf for Omega/(1+Omega) (v_sin/v_cos
// collapse to exact 0 at l=8192 -> NaN). FFT twiddles use __sincosf.

#define D_DIM 512
#define NFFT 16384
#define TWO_PI_F 6.283185307179586f
#define PI_F 3.14159265358979323846f

struct C2 { float x, y; };
struct C4 { C2 a, b; };   // two consecutive d columns

__device__ __forceinline__ C2 cmul(C2 a, C2 b){ return C2{a.x*b.x - a.y*b.y, a.x*b.y + a.y*b.x}; }
__device__ __forceinline__ C2 cadd(C2 a, C2 b){ return C2{a.x+b.x, a.y+b.y}; }
__device__ __forceinline__ C2 csub(C2 a, C2 b){ return C2{a.x-b.x, a.y-b.y}; }
__device__ __forceinline__ C2 cdiv(C2 a, C2 b){
  float inv = 1.f/(b.x*b.x + b.y*b.y);
  return C2{(a.x*b.x + a.y*b.y)*inv, (a.y*b.x - a.x*b.y)*inv};
}
__device__ __forceinline__ void cfma_(C2& acc, C2 a, C2 b){
  acc.x = fmaf(a.x, b.x, fmaf(-a.y, b.y, acc.x));
  acc.y = fmaf(a.x, b.y, fmaf( a.y, b.x, acc.y));
}
__device__ __forceinline__ C4 ld16(const C2* p){
  float4 t = *(const float4*)p;
  return C4{ C2{t.x,t.y}, C2{t.z,t.w} };
}

template<bool INV>
__device__ __forceinline__ void dft4(C2& a, C2& b, C2& c, C2& d){
  C2 t0 = cadd(a,c), t1 = csub(a,c), t2 = cadd(b,d), t3 = csub(b,d);
  C2 it3 = INV ? C2{-t3.y, t3.x} : C2{t3.y, -t3.x};
  a = cadd(t0,t2); c = csub(t0,t2); b = cadd(t1,it3); d = csub(t1,it3);
}

template<bool INV>
__device__ __forceinline__ void twd(C2& v, float c, float s){
  C2 w{c, INV ? s : -s};
  v = cmul(v, w);
}

// In-place 16-pt DFT (DIT 4x4). Output X[s] at v[perm16(s)], perm16(s)=4*(s&3)+(s>>2).
template<bool INV>
__device__ __forceinline__ void dft16(C2 v[16]){
  dft4<INV>(v[0], v[4], v[8],  v[12]);
  dft4<INV>(v[1], v[5], v[9],  v[13]);
  dft4<INV>(v[2], v[6], v[10], v[14]);
  dft4<INV>(v[3], v[7], v[11], v[15]);
  const float C1 = 0.9238795325112867f, S1 = 0.3826834323650898f;
  const float CQ = 0.7071067811865476f;
  const float C3 = 0.3826834323650898f, S3 = 0.9238795325112867f;
  twd<INV>(v[5],  C1,  S1);
  twd<INV>(v[9],  CQ,  CQ);
  twd<INV>(v[13], C3,  S3);
  twd<INV>(v[6],  CQ,  CQ);
  twd<INV>(v[10], 0.f, 1.f);
  twd<INV>(v[14], -CQ, CQ);
  twd<INV>(v[7],  C3,  S3);
  twd<INV>(v[11], -CQ, CQ);
  twd<INV>(v[15], -C1, -S1);
  dft4<INV>(v[0],  v[1],  v[2],  v[3]);
  dft4<INV>(v[4],  v[5],  v[6],  v[7]);
  dft4<INV>(v[8],  v[9],  v[10], v[11]);
  dft4<INV>(v[12], v[13], v[14], v[15]);
}

// 8-pt DFT, natural-order in/out.
template<bool INV>
__device__ __forceinline__ void dft8(C2 v[8]){
  C2 e0=v[0], e1=v[2], e2=v[4], e3=v[6];
  C2 o0=v[1], o1=v[3], o2=v[5], o3=v[7];
  dft4<INV>(e0,e1,e2,e3);
  dft4<INV>(o0,o1,o2,o3);
  const float r = 0.7071067811865476f;
  C2 w1 = INV ? C2{r, r}    : C2{r, -r};
  C2 w2 = INV ? C2{0.f,1.f} : C2{0.f,-1.f};
  C2 w3 = INV ? C2{-r, r}   : C2{-r, -r};
  C2 t0=o0, t1=cmul(o1,w1), t2=cmul(o2,w2), t3=cmul(o3,w3);
  v[0]=cadd(e0,t0); v[4]=csub(e0,t0);
  v[1]=cadd(e1,t1); v[5]=csub(e1,t1);
  v[2]=cadd(e2,t2); v[6]=csub(e2,t2);
  v[3]=cadd(e3,t3); v[7]=csub(e3,t3);
}

// Shared stage-1 tail: twiddle W128^{sgn*j1*k2} applied to both d-columns,
// then float4 LDS write at [(k2*16+j1)*32 + 2*dp].
template<bool INV>
__device__ __forceinline__ void stage1_tail(C2 vA[8], C2 vB[8], int j1, int dp, C2* V){
  const float sgn = INV ? 1.f : -1.f;
  dft8<INV>(vA);
  dft8<INV>(vB);
  float sn, cs; __sincosf(sgn * TWO_PI_F * (float)j1 * (1.f/128.f), &sn, &cs);
  C2 w1{cs, sn}; C2 w = w1;
  #pragma unroll
  for (int k2=1;k2<8;k2++){
    vA[k2] = cmul(vA[k2], w);
    vB[k2] = cmul(vB[k2], w);
    w = cmul(w, w1);
  }
  #pragma unroll
  for (int k2=0;k2<8;k2++){
    int idx = (k2*16 + j1)*32 + 2*dp;          // 16B-aligned
    *(float4*)&V[idx] = make_float4(vA[k2].x, vA[k2].y, vB[k2].x, vB[k2].y);
  }
}

// Shared stage-2 for sweep1-type kernels: read y[16], dft16, outer twiddle
// W_N^{sgn*a*(g+8k1)}, write row (g+8k1)*128 + a.
template<bool INV>
__device__ __forceinline__ void sweep1_stage2(const C2* V, int a, int g, int dl, int d0, C2* ob){
  const float sgn = INV ? 1.f : -1.f;
  C2 y[16];
  #pragma unroll
  for (int j1=0;j1<16;j1++) y[j1] = V[(g*16 + j1)*32 + dl];
  dft16<INV>(y);
  float sb_, cb_; __sincosf(sgn * TWO_PI_F * (float)(a*g) * (1.f/16384.f), &sb_, &cb_);
  float ss_, cs2; __sincosf(sgn * TWO_PI_F * (float)(8*a)  * (1.f/16384.f), &ss_, &cs2);
  C2 tw{cb_, sb_}; C2 stp{cs2, ss_};
  #pragma unroll
  for (int k1=0;k1<16;k1++){
    int pidx = ((k1&3)<<2) | (k1>>2);
    C2 val = cmul(y[pidx], tw);
    int k2p = g + 8*k1;
    ob[(long long)(k2p*128 + a)*D_DIM + d0] = val;
    tw = cmul(tw, stp);
  }
}

// ============ Sweep 1 of four-step FFT (N=16384=128x128) ====================
// Block: a=n1 in [0,128), d-tile of 32. Stage1: dp=tid&15 (2 d), j1=tid>>4;
// reads rows a+128*(j1+16*j2). Stage2: dl=tid&31, g=tid>>5.
// PACK: x[r]=src[2r]+i*src[2r+1] for r<8192, else 0.
template<bool INV, bool PACK>
__global__ __launch_bounds__(256) void k_sweep1(const void* __restrict__ srcv, C2* __restrict__ out,
                                                long long src_bstride, long long out_bstride){
  __shared__ C2 V[128*32];
  int bx = blockIdx.x;
  int a  = bx & 127;
  int dt = bx >> 7;
  int tid = threadIdx.x;
  int dp = tid & 15;
  int j1 = tid >> 4;
  int d0p = dt*32 + 2*dp;
  C2* ob = out + (long long)blockIdx.y * out_bstride;

  C2 vA[8], vB[8];
  if constexpr (PACK){
    const float* sb = (const float*)srcv + (long long)blockIdx.y * src_bstride;
    #pragma unroll
    for (int j2=0;j2<4;j2++){
      int rr = a + 128*(j1 + 16*j2);            // j<64 exactly
      float2 e = *(const float2*)&sb[(long long)(2*rr)  *D_DIM + d0p];
      float2 o = *(const float2*)&sb[(long long)(2*rr+1)*D_DIM + d0p];
      vA[j2] = C2{e.x, o.x};
      vB[j2] = C2{e.y, o.y};
    }
    #pragma unroll
    for (int j2=4;j2<8;j2++){ vA[j2] = C2{0.f,0.f}; vB[j2] = C2{0.f,0.f}; }
  } else {
    const C2* sb = (const C2*)srcv + (long long)blockIdx.y * src_bstride;
    #pragma unroll
    for (int j2=0;j2<8;j2++){
      int rr = a + 128*(j1 + 16*j2);
      C4 t = ld16(&sb[(long long)rr*D_DIM + d0p]);
      vA[j2] = t.a; vB[j2] = t.b;
    }
  }
  stage1_tail<INV>(vA, vB, j1, dp, V);
  __syncthreads();
  int dl = tid & 31, g = tid >> 5;
  sweep1_stage2<INV>(V, a, g, dl, dt*32 + dl, ob);
}

// ---- fused spectral multiply (per row rr, d column pair handled by caller) -
__device__ __forceinline__ C2 fuse_mul(C2 zk_, C2 zm_, C2 hk_, C2 hm_, float cw, float sw){
  C2 w  { cw, -sw};
  C2 wm {-cw, -sw};
  C2 Ze  {0.5f*(zk_.x + zm_.x), 0.5f*(zk_.y - zm_.y)};
  C2 Zo  {0.5f*(zk_.y + zm_.y), -0.5f*(zk_.x - zm_.x)};
  C2 Xk = cadd(Ze, cmul(w, Zo));
  C2 Zem {0.5f*(zm_.x + zk_.x), 0.5f*(zm_.y - zk_.y)};
  C2 Zom {0.5f*(zm_.y + zk_.y), -0.5f*(zm_.x - zk_.x)};
  C2 Xm = cadd(Zem, cmul(wm, Zom));
  C2 KZe  {0.5f*(hk_.x + hm_.x), 0.5f*(hk_.y - hm_.y)};
  C2 KZo  {0.5f*(hk_.y + hm_.y), -0.5f*(hk_.x - hm_.x)};
  C2 Hk = cadd(KZe, cmul(w, KZo));
  C2 KZem {0.5f*(hm_.x + hk_.x), 0.5f*(hm_.y - hk_.y)};
  C2 KZom {0.5f*(hm_.y + hk_.y), -0.5f*(hm_.x - hk_.x)};
  C2 Hm = cadd(KZem, cmul(wm, KZom));
  C2 Yk = cmul(Xk, Hk);
  C2 Ym = cmul(Xm, Hm);
  C2 E  {0.5f*(Yk.x + Ym.x), 0.5f*(Yk.y - Ym.y)};
  C2 T  {0.5f*(Yk.x - Ym.x), 0.5f*(Yk.y + Ym.y)};
  C2 wp { cw, sw};
  C2 O = cmul(wp, T);
  return C2{E.x - O.y, E.y + O.x};
}

// ===== FUSED spectral-multiply + inverse sweep1 (u path) =====================
// Z'[rr] computed on the fly from Zu[rr], Zu[mr], ZK[rr], ZK[mr]; then the
// usual inverse 128-pt DFT + outer twiddle. Mirror tiles pair-share in L2/L3.
__global__ __launch_bounds__(256) void k_sweep1m(const C2* __restrict__ Zu, const C2* __restrict__ ZK,
                                                 C2* __restrict__ out, long long bstride){
  __shared__ C2 V[128*32];
  int bx = blockIdx.x;
  int a  = bx & 127;
  int dt = bx >> 7;
  int tid = threadIdx.x;
  int dp = tid & 15;
  int j1 = tid >> 4;
  int d0p = dt*32 + 2*dp;
  const C2* zub = Zu + (long long)blockIdx.y * bstride;
  C2* ob = out + (long long)blockIdx.y * bstride;

  C2 vA[8], vB[8];
  #pragma unroll
  for (int j2=0;j2<8;j2++){
    int rr = a + 128*(j1 + 16*j2);
    int mr = (NFFT - rr) & (NFFT - 1);
    C4 zk_ = ld16(&zub[(long long)rr*D_DIM + d0p]);
    C4 zm_ = ld16(&zub[(long long)mr*D_DIM + d0p]);
    C4 hk_ = ld16(&ZK [(long long)rr*D_DIM + d0p]);
    C4 hm_ = ld16(&ZK [(long long)mr*D_DIM + d0p]);
    float sw, cw; __sincosf(PI_F * (float)rr / 16384.f, &sw, &cw);
    vA[j2] = fuse_mul(zk_.a, zm_.a, hk_.a, hm_.a, cw, sw);
    vB[j2] = fuse_mul(zk_.b, zm_.b, hk_.b, hm_.b, cw, sw);
  }
  stage1_tail<true>(vA, vB, j1, dp, V);
  __syncthreads();
  int dl = tid & 31, g = tid >> 5;
  sweep1_stage2<true>(V, a, g, dl, dt*32 + dl, ob);
}

// ============ Sweep 2: block a=k2, reads contiguous rows a*128+j =============
// Stage1: dp/j1 mapping, rows a*128 + j1 + 16*j2, float4 loads.
// Stage2: writes row a + 128*(g+8k1) (natural final order).
// OMODE 0: C2 out. 1: real part to float (Kreal). 2: y-fused unpack+scale+D*u.
template<bool INV, int OMODE>
__global__ __launch_bounds__(256) void k_sweep2(const C2* __restrict__ in, void* __restrict__ outv,
                                                const float* __restrict__ u, const float* __restrict__ Dp,
                                                long long in_bstride, long long out_bstride){
  __shared__ C2 V[128*32];
  int bx = blockIdx.x;
  int a  = bx & 127;
  int dt = bx >> 7;
  int tid = threadIdx.x;
  int dp = tid & 15;
  int j1 = tid >> 4;
  int d0p = dt*32 + 2*dp;
  const C2* ib = in + (long long)blockIdx.y * in_bstride;

  C2 vA[8], vB[8];
  #pragma unroll
  for (int j2=0;j2<8;j2++){
    int rr = a*128 + (j1 + 16*j2);
    C4 t = ld16(&ib[(long long)rr*D_DIM + d0p]);
    vA[j2] = t.a; vB[j2] = t.b;
  }
  stage1_tail<INV>(vA, vB, j1, dp, V);
  __syncthreads();
  int dl = tid & 31, g = tid >> 5;
  int d0 = dt*32 + dl;
  C2 y[16];
  #pragma unroll
  for (int j1b=0;j1b<16;j1b++) y[j1b] = V[(g*16 + j1b)*32 + dl];
  dft16<INV>(y);
  #pragma unroll
  for (int k1=0;k1<16;k1++){
    int pidx = ((k1&3)<<2) | (k1>>2);
    C2 val = y[pidx];
    int row = a + 128*(g + 8*k1);
    if constexpr (OMODE == 0){
      C2* ob = (C2*)outv + (long long)blockIdx.y * out_bstride;
      ob[(long long)row*D_DIM + d0] = val;
    } else if constexpr (OMODE == 1){
      float* ob = (float*)outv;
      ob[(long long)row*D_DIM + d0] = val.x;
    } else {
      if (row < 8192){                            // uniform: k1<8
        float* yb = (float*)outv + (long long)blockIdx.y * out_bstride;
        const float* ub = u + (long long)blockIdx.y * out_bstride;
        float dpv = Dp[0];
        const float invN = 1.f/16384.f;
        yb[(long long)(2*row)  *D_DIM + d0] = fmaf(dpv, ub[(long long)(2*row)  *D_DIM + d0], val.x*invN);
        yb[(long long)(2*row+1)*D_DIM + d0] = fmaf(dpv, ub[(long long)(2*row+1)*D_DIM + d0], val.y*invN);
      }
    }
  }
}

// ---------------- parameter prep: U0=conj(C)*B, U1=conj(P)*B, vecs ---------
__global__ __launch_bounds__(256) void k_prep(const float* __restrict__ B_ri, const float* __restrict__ C_ri,
                                              const float* __restrict__ P_ri,
                                              C2* __restrict__ U0, C2* __restrict__ U1, C2* __restrict__ vecs){
  int idx = blockIdx.x*256 + threadIdx.x;          // [0, 64*512)
  int n = idx >> 9;
  C2 Bnd { B_ri[2*idx], B_ri[2*idx+1] };
  C2 Cc  { C_ri[2*n], -C_ri[2*n+1] };
  C2 Pc  { P_ri[2*n], -P_ri[2*n+1] };
  U0[idx] = cmul(Cc, Bnd);
  U1[idx] = cmul(Pc, Bnd);
  if ((idx & (D_DIM-1)) == 0){
    C2 Pn { P_ri[2*n], P_ri[2*n+1] };
    vecs[n]       = cmul(Cc, Pn);
    vecs[64 + n]  = cmul(Pc, Pn);
  }
}

// ---- weight precompute: W tiles of 8 l-rows: [l>>3][n'][l&7], n' in [0,128) -
__global__ __launch_bounds__(256) void k_wprep(const float* __restrict__ Lambda_ri,
                                               const float* __restrict__ log_step,
                                               const C2* __restrict__ vecs,
                                               C2* __restrict__ Wbuf){
  __shared__ C2 p01[4][64];
  __shared__ C2 p11[4][64];
  __shared__ C2 sA1[64];
  int tid = threadIdx.x;
  int li = tid & 63, q = tid >> 6;
  int l = blockIdx.x*64 + li;
  float step = expf(log_step[0]);
  float ang = -TWO_PI_F * (float)l / 16384.f;
  float sn, cs; sincosf(ang, &sn, &cs);            // accurate (l=8192 collapse!)
  C2 den{1.f+cs, sn};
  C2 num{1.f-cs, -sn};
  C2 r = cdiv(num, den);
  float s2 = 2.f/step;
  C2 gl{r.x*s2, r.y*s2};
  C2 alpha = cdiv(C2{2.f/16384.f, 0.f}, den);      // (2/(1+Om)) * (1/L)
  C2 c[16]; C2 k01{0,0}, k11{0,0};
  #pragma unroll
  for (int i=0;i<16;i++){
    int n = q*16+i;
    C2 lam{Lambda_ri[2*n], Lambda_ri[2*n+1]};
    c[i] = cdiv(C2{1.f,0.f}, C2{gl.x-lam.x, gl.y-lam.y});
    cfma_(k01, c[i], vecs[n]);
    cfma_(k11, c[i], vecs[64+n]);
  }
  p01[q][li] = k01; p11[q][li] = k11;
  __syncthreads();
  if (q==0){
    C2 s01 = cadd(cadd(p01[0][li],p01[1][li]),cadd(p01[2][li],p01[3][li]));
    C2 s11 = cadd(cadd(p11[0][li],p11[1][li]),cadd(p11[2][li],p11[3][li]));
    C2 beta = cdiv(s01, C2{1.f+s11.x, s11.y});
    C2 ab = cmul(alpha, beta);
    sA1[li] = C2{-ab.x, -ab.y};
  }
  __syncthreads();
  C2 A1 = sA1[li];
  size_t base = (size_t)(l>>3)*(128*8) + (size_t)(l&7);
  #pragma unroll
  for (int i=0;i<16;i++){
    int n = q*16+i;
    Wbuf[base + (size_t)n*8]      = cmul(alpha, c[i]);
    Wbuf[base + (size_t)(64+n)*8] = cmul(A1, c[i]);
  }
}

// ---- ev GEMM: ev[l,d] = sum_{n'} W[l,n'] * U[n',d]. W wave-uniform (s_load).
__global__ __launch_bounds__(256) void k_ev2(const C2* __restrict__ U, const C2* __restrict__ Wbuf,
                                             C2* __restrict__ ev){
  int tid = threadIdx.x;
  int tile = blockIdx.x;               // [0,2048) : 8 l-rows each
  int d0 = tid, d1 = tid + 256;
  const C2* __restrict__ Wt = Wbuf + (size_t)tile*(128*8);
  C2 acc0[8], acc1[8];
  #pragma unroll
  for (int li=0;li<8;li++){ acc0[li]=C2{0.f,0.f}; acc1[li]=C2{0.f,0.f}; }
  C2 u0 = U[d0], u1 = U[d1];
  for (int np=0; np<128; ++np){
    C2 nu0 = U[(size_t)(np+1)*D_DIM + d0];   // np=127 overreads into RB scratch: safe
    C2 nu1 = U[(size_t)(np+1)*D_DIM + d1];
    const C2* wr = Wt + (size_t)np*8;
    #pragma unroll
    for (int li=0;li<8;li++){
      C2 w = wr[li];
      cfma_(acc0[li], w, u0);
      cfma_(acc1[li], w, u1);
    }
    u0 = nu0; u1 = nu1;
  }
  long long l0 = (long long)tile*8;
  #pragma unroll
  for (int li=0;li<8;li++){
    ev[(l0+li)*D_DIM + d0] = acc0[li];
    ev[(l0+li)*D_DIM + d1] = acc1[li];
  }
}

extern "C" void kernel_launch(void* const* d_in, const int* in_sizes, int n_in,
                              void* d_out, int out_size, void* d_ws, size_t ws_size,
                              hipStream_t stream){
  const float* u         = (const float*)d_in[0];
  const float* Lambda_ri = (const float*)d_in[1];
  const float* P_ri      = (const float*)d_in[2];
  const float* B_ri      = (const float*)d_in[3];
  const float* C_ri      = (const float*)d_in[4];
  const float* Dp        = (const float*)d_in[5];
  const float* log_step  = (const float*)d_in[6];
  float* y = (float*)d_out;

  const long long ND = (long long)NFFT * D_DIM;      // 8,388,608 elements
  const size_t SZ = (size_t)ND * sizeof(C2);         // 64 MiB

  int bc = 4;
  if (ws_size < (size_t)(2*4+1)*SZ) bc = 2;
  if (ws_size < (size_t)(2*2+1)*SZ) bc = 1;
  if (ws_size < (size_t)3*SZ) return;

  char* base = (char*)d_ws;
  C2* RA = (C2*)base;                                // bc * 64 MiB ping
  C2* RB = (C2*)(base + (size_t)bc*SZ);              // bc * 64 MiB pong
  C2* RC = (C2*)(base + (size_t)2*bc*SZ);            // 64 MiB: Wbuf -> Kreal -> ZK
  C2* Wbuf  = RC;                                    // 16.7 MiB (dead after k_ev2)
  float* Kreal = (float*)RC;                         // 32 MiB (dead after K-fwd sweep1)
  C2* U0   = RB;
  C2* U1   = RB + 64*D_DIM;
  C2* vecs = RB + 2*64*D_DIM;
  C2* U    = RB;

  dim3 blk(256);

  // ---- params + evaluated (scaled 1/L) into RA ----
  k_prep <<<dim3(128),  blk, 0, stream>>>(B_ri, C_ri, P_ri, U0, U1, vecs);
  k_wprep<<<dim3(256),  blk, 0, stream>>>(Lambda_ri, log_step, vecs, Wbuf);
  k_ev2  <<<dim3(2048), blk, 0, stream>>>(U, Wbuf, RA);

  // ---- K path: ifft_L(ev) -> Kreal ; rfft_2L(K) packed -> ZK (RC) ----
  k_sweep1<true,false><<<dim3(2048,1), blk, 0, stream>>>(RA, RB, 0LL, 0LL);
  k_sweep2<true,1>    <<<dim3(2048,1), blk, 0, stream>>>(RB, Kreal, nullptr, nullptr, 0LL, 0LL);
  k_sweep1<false,true><<<dim3(2048,1), blk, 0, stream>>>(Kreal, RA, 0LL, 0LL);
  k_sweep2<false,0>   <<<dim3(2048,1), blk, 0, stream>>>(RA, RC, nullptr, nullptr, 0LL, 0LL);  // ZK

  // ---- u path (chunked over batch) ----
  for (int b0 = 0; b0 < 4; b0 += bc){
    const float* ub = u + (long long)b0 * ND;
    float*       yb = y + (long long)b0 * ND;
    k_sweep1<false,true><<<dim3(2048,bc), blk, 0, stream>>>(ub, RA, ND, ND);
    k_sweep2<false,0>   <<<dim3(2048,bc), blk, 0, stream>>>(RA, RB, nullptr, nullptr, ND, ND); // Zu
    k_sweep1m           <<<dim3(2048,bc), blk, 0, stream>>>(RB, RC, RA, ND);                   // mul+inv s1
    k_sweep2<true,2>    <<<dim3(2048,bc), blk, 0, stream>>>(RA, yb, ub, Dp, ND, ND);           // y
  }
}